// Round 13
// baseline (171.636 us; speedup 1.0000x reference)
//
#include <hip/hip_runtime.h>
#include <hip/hip_fp16.h>

// ODEFunc CNF dynamics, B=1e6 rows, H=64:
//   h1 = elu(W1 z + b1); h2 = W2 h1 + b2; out01 = W3 elu(h2)+b3;
//   trace = sum_k elu'(h2_k) * (G ex1)_k with G[k,j]=W2[k,j]*(c_k w0_j + d_k w1_j)
//
// Ladder: R6 74 -> R8 62.5 -> R10 58 -> R11 55.3 -> R12 f16 layer-1 52 ->
// R15 (3,3) 50.6 -> R16 consts->regs 49.5 -> R18 l2e-fold + f16 epilogue 46.5.
// R18 counters: VALUBusy ~50% at 2 waves -> HALF the wall is stall (my R16
// "wall==issue demand" model was wrong; issue fills only ~50%). Both waves
// stall together on exp/trans chains. A 3rd wave = one more independent
// stream to fill stall slots. R15 precedent: same change on R12 structure
// gave +3%. Spill risk zero: VGPR 112 << (3,3) cap 168; (3,3) never spilled
// (R7 68, R10 84, R15 84).
// R19 (this): single isolated change — waves_per_eu(2,2)->(3,3), grid 1536.
//   Spill litmus: WRITE_SIZE must stay 11718.75 KB, FETCH ~5988 KB.
// Layouts (m120-verified): A[m=col][k=jt*32+quad*8+jj], B[k][n=col],
//   D[m=mt*16+quad*4+i][n=col].

typedef _Float16 f16x8 __attribute__((ext_vector_type(8)));
typedef _Float16 f16x2 __attribute__((ext_vector_type(2)));
typedef float    f32x4 __attribute__((ext_vector_type(4)));

static __device__ __forceinline__ f16x8 exp2_h8(f16x8 t) {
    f16x8 e;
#pragma unroll
    for (int p = 0; p < 4; ++p) {
        f16x2 t2 = {t[2*p], t[2*p+1]};
        __half2 r = h2exp2(__builtin_bit_cast(__half2, t2));
        f16x2 e2 = __builtin_bit_cast(f16x2, r);
        e[2*p] = e2[0]; e[2*p+1] = e2[1];
    }
    return e;
}

static __device__ __forceinline__ f16x2 exp2_h2(f16x2 t) {
    __half2 r = h2exp2(__builtin_bit_cast(__half2, t));
    return __builtin_bit_cast(f16x2, r);
}

static __device__ __forceinline__ f16x2 cvtpk(float a, float b) {
    return __builtin_bit_cast(f16x2, __builtin_amdgcn_cvt_pkrtz(a, b));
}

__global__ __launch_bounds__(256) __attribute__((amdgpu_waves_per_eu(3, 3)))
void odefunc_mfma(const float* __restrict__ zin,
                  const float* __restrict__ W1, const float* __restrict__ b1,
                  const float* __restrict__ W2, const float* __restrict__ b2,
                  const float* __restrict__ W3, const float* __restrict__ b3,
                  float* __restrict__ out, int B, int ntiles)
{
    const float L2E  = 1.442695040888963f;
    const float RL2E = 0.6931471805599453f;   // 1/log2(e) = ln 2

    // LDS: one-shot staging for coalesced const loads (pre-scaled by l2e fold)
    __shared__ _Float16 sH[192];   // l2e*W1 col0 | l2e*W1 col1 | l2e*b1
    __shared__ f32x4    sC[48];    // l2e*b2 | W3row0/l2e | W3row1/l2e

    const int lane = threadIdx.x & 63;
    const int quad = lane >> 4;      // 0..3
    const int col  = lane & 15;      // row-within-tile

    if (threadIdx.x < 64) {
        int i = threadIdx.x;
        sH[i]       = (_Float16)(W1[2*i]     * L2E);
        sH[64 + i]  = (_Float16)(W1[2*i + 1] * L2E);
        sH[128 + i] = (_Float16)(b1[i]       * L2E);
        float* s = (float*)sC;
        s[i]       = b2[i] * L2E;
        s[64 + i]  = W3[i]      * RL2E;   // W3[0,:]/l2e
        s[128 + i] = W3[64 + i] * RL2E;   // W3[1,:]/l2e
    }

    const int wid    = blockIdx.x * (blockDim.x >> 6) + (threadIdx.x >> 6);
    const int nwaves = gridDim.x * (blockDim.x >> 6);

    // ---- Loop-invariant A-fragments (f16): W2 and G (trace-folded), UNSCALED ----
    f16x8 aW2[4][2], aG[4][2];
#pragma unroll
    for (int mt = 0; mt < 4; ++mt) {
        const int k = mt * 16 + col;
        const float ck = W3[k], dk = W3[64 + k];
#pragma unroll
        for (int jt = 0; jt < 2; ++jt) {
            const float* p = W2 + k * 64 + jt * 32 + quad * 8;
#pragma unroll
            for (int jj = 0; jj < 8; ++jj) {
                int j = jt * 32 + quad * 8 + jj;
                float w2 = p[jj];
                aW2[mt][jt][jj] = (_Float16)w2;
                aG[mt][jt][jj]  = (_Float16)(w2 * fmaf(ck, W1[2*j], dk * W1[2*j+1]));
            }
        }
    }

    const float b30 = b3[0], b31 = b3[1];
    const f32x4 zero4 = {0.f, 0.f, 0.f, 0.f};
    const _Float16 hl2e = (_Float16)L2E;
    const _Float16 h0   = (_Float16)0.0f;
    const f16x8 zero8 = {h0,h0,h0,h0,h0,h0,h0,h0};
    const f16x8 l2e8  = {hl2e,hl2e,hl2e,hl2e,hl2e,hl2e,hl2e,hl2e};
    const f16x8 ml2e8 = {-hl2e,-hl2e,-hl2e,-hl2e,-hl2e,-hl2e,-hl2e,-hl2e};
    const f16x2 zero2 = {h0, h0};
    const f16x2 l2e2  = {hl2e, hl2e};
    const f16x2 ml2e2 = {-hl2e, -hl2e};

    __syncthreads();

    // ---- hoist per-lane constants into registers ----
    f16x8 cw0[2], cw1[2], cbb[2];
#pragma unroll
    for (int jt = 0; jt < 2; ++jt) {
        int j0 = jt * 32 + quad * 8;
        cw0[jt] = *(const f16x8*)(sH + j0);
        cw1[jt] = *(const f16x8*)(sH + j0 + 64);
        cbb[jt] = *(const f16x8*)(sH + j0 + 128);
    }
    f32x4 cb2[4];
    f16x2 cw30h[4][2], cw31h[4][2];
#pragma unroll
    for (int mt = 0; mt < 4; ++mt) {
        int k4 = mt * 4 + quad;
        cb2[mt] = sC[k4];                       // l2e*b2 -> MFMA C-init
        f32x4 w30 = sC[k4 + 16];
        f32x4 w31 = sC[k4 + 32];
        cw30h[mt][0] = cvtpk(w30[0], w30[1]);
        cw30h[mt][1] = cvtpk(w30[2], w30[3]);
        cw31h[mt][0] = cvtpk(w31[0], w31[1]);
        cw31h[mt][1] = cvtpk(w31[2], w31[3]);
    }

    // ---- coalesced z: lanes 0-47 cover a tile's 16 rows x 3 floats ----
    const int lload = lane < 48 ? lane : 47;
    int tp = wid;                     // tile-pair index: tiles 2tp, 2tp+1
    float zvA = 0.f, zvB = 0.f;
    if (2 * tp < ntiles) {
        zvA = zin[(2 * tp) * 48 + lload];
        if (2 * tp + 1 < ntiles) zvB = zin[(2 * tp + 1) * 48 + lload];
    }

    for (; 2 * tp < ntiles; tp += nwaves) {
        const int tA = 2 * tp, tB = 2 * tp + 1;
        const bool vB = tB < ntiles;

        // prefetch next pair's z (covered by this pair's ~4k-cycle body)
        int tpn = tp + nwaves;
        int tAn = 2 * tpn     < ntiles ? 2 * tpn     : 0;
        int tBn = 2 * tpn + 1 < ntiles ? 2 * tpn + 1 : 0;
        float zvAn = zin[tAn * 48 + lload];
        float zvBn = zin[tBn * 48 + lload];

        float z0A = __shfl(zvA, 3 * col), z1A = __shfl(zvA, 3 * col + 1);
        float z0B = __shfl(zvB, 3 * col), z1B = __shfl(zvB, 3 * col + 1);
        const _Float16 z0Ah = (_Float16)z0A, z1Ah = (_Float16)z1A;
        const _Float16 z0Bh = (_Float16)z0B, z1Bh = (_Float16)z1B;
        const f16x8 z0A8 = {z0Ah,z0Ah,z0Ah,z0Ah,z0Ah,z0Ah,z0Ah,z0Ah};
        const f16x8 z1A8 = {z1Ah,z1Ah,z1Ah,z1Ah,z1Ah,z1Ah,z1Ah,z1Ah};
        const f16x8 z0B8 = {z0Bh,z0Bh,z0Bh,z0Bh,z0Bh,z0Bh,z0Bh,z0Bh};
        const f16x8 z1B8 = {z1Bh,z1Bh,z1Bh,z1Bh,z1Bh,z1Bh,z1Bh,z1Bh};

        // ---- layer 1: a' = l2e*a (pre-scaled consts); e = exp2(min(a',0));
        //      Bh' = l2e*elu(a) = max(a', fma(l2e,e,-l2e)) ----
        f16x8 BhA[2], BeA[2], BhB[2], BeB[2];
#pragma unroll
        for (int jt = 0; jt < 2; ++jt) {
            // tile A
            f16x8 aA = __builtin_elementwise_fma(cw0[jt], z0A8,
                       __builtin_elementwise_fma(cw1[jt], z1A8, cbb[jt]));
            f16x8 eA = exp2_h8(__builtin_elementwise_min(aA, zero8));
            f16x8 hA = __builtin_elementwise_max(aA,
                       __builtin_elementwise_fma(l2e8, eA, ml2e8));
            // tile B (independent chain)
            f16x8 aB = __builtin_elementwise_fma(cw0[jt], z0B8,
                       __builtin_elementwise_fma(cw1[jt], z1B8, cbb[jt]));
            f16x8 eB = exp2_h8(__builtin_elementwise_min(aB, zero8));
            f16x8 hB = __builtin_elementwise_max(aB,
                       __builtin_elementwise_fma(l2e8, eB, ml2e8));
            BhA[jt] = hA; BeA[jt] = eA;
            BhB[jt] = hB; BeB[jt] = eB;
        }

        // ---- MFMA: accH = W2*(l2e*h) + l2e*b2 = l2e*h2pre; accT = G*e ----
        f32x4 aHA[4], aTA[4], aHB[4], aTB[4];
#pragma unroll
        for (int mt = 0; mt < 4; ++mt) {
            aHA[mt] = __builtin_amdgcn_mfma_f32_16x16x32_f16(aW2[mt][0], BhA[0], cb2[mt], 0, 0, 0);
            aHA[mt] = __builtin_amdgcn_mfma_f32_16x16x32_f16(aW2[mt][1], BhA[1], aHA[mt], 0, 0, 0);
            aHB[mt] = __builtin_amdgcn_mfma_f32_16x16x32_f16(aW2[mt][0], BhB[0], cb2[mt], 0, 0, 0);
            aHB[mt] = __builtin_amdgcn_mfma_f32_16x16x32_f16(aW2[mt][1], BhB[1], aHB[mt], 0, 0, 0);
            aTA[mt] = __builtin_amdgcn_mfma_f32_16x16x32_f16(aG[mt][0], BeA[0], zero4, 0, 0, 0);
            aTA[mt] = __builtin_amdgcn_mfma_f32_16x16x32_f16(aG[mt][1], BeA[1], aTA[mt], 0, 0, 0);
            aTB[mt] = __builtin_amdgcn_mfma_f32_16x16x32_f16(aG[mt][0], BeB[0], zero4, 0, 0, 0);
            aTB[mt] = __builtin_amdgcn_mfma_f32_16x16x32_f16(aG[mt][1], BeB[1], aTB[mt], 0, 0, 0);
        }

        // ---- epilogue (packed f16, true double-rate): e2 = exp2(min(acc,0));
        //      hh' = max(acc, fma(l2e,e2,-l2e)); folds in pk_fma_f16 ----
        f16x2 o0A2 = zero2, o1A2 = zero2, trA2 = zero2;
        f16x2 o0B2 = zero2, o1B2 = zero2, trB2 = zero2;
#pragma unroll
        for (int mt = 0; mt < 4; ++mt) {
#pragma unroll
            for (int p = 0; p < 2; ++p) {
                f16x2 w30p = cw30h[mt][p], w31p = cw31h[mt][p];
                // tile A
                f16x2 ahA = cvtpk(aHA[mt][2*p], aHA[mt][2*p+1]);
                f16x2 atA = cvtpk(aTA[mt][2*p], aTA[mt][2*p+1]);
                f16x2 eA  = exp2_h2(__builtin_elementwise_min(ahA, zero2));
                f16x2 hhA = __builtin_elementwise_max(ahA,
                            __builtin_elementwise_fma(l2e2, eA, ml2e2));
                o0A2 = __builtin_elementwise_fma(w30p, hhA, o0A2);
                o1A2 = __builtin_elementwise_fma(w31p, hhA, o1A2);
                trA2 = __builtin_elementwise_fma(eA, atA, trA2);
                // tile B
                f16x2 ahB = cvtpk(aHB[mt][2*p], aHB[mt][2*p+1]);
                f16x2 atB = cvtpk(aTB[mt][2*p], aTB[mt][2*p+1]);
                f16x2 eB  = exp2_h2(__builtin_elementwise_min(ahB, zero2));
                f16x2 hhB = __builtin_elementwise_max(ahB,
                            __builtin_elementwise_fma(l2e2, eB, ml2e2));
                o0B2 = __builtin_elementwise_fma(w30p, hhB, o0B2);
                o1B2 = __builtin_elementwise_fma(w31p, hhB, o1B2);
                trB2 = __builtin_elementwise_fma(eB, atB, trB2);
            }
        }
        float o0a = (float)o0A2[0] + (float)o0A2[1];
        float o1a = (float)o1A2[0] + (float)o1A2[1];
        float tra = (float)trA2[0] + (float)trA2[1];
        float o0b = (float)o0B2[0] + (float)o0B2[1];
        float o1b = (float)o1B2[0] + (float)o1B2[1];
        float trb = (float)trB2[0] + (float)trB2[1];

        // ---- cross-quad reduction (k spans quads): 2 butterfly stages, f32 ----
        o0a += __shfl_xor(o0a, 16); o0a += __shfl_xor(o0a, 32);
        o1a += __shfl_xor(o1a, 16); o1a += __shfl_xor(o1a, 32);
        tra += __shfl_xor(tra, 16); tra += __shfl_xor(tra, 32);
        o0b += __shfl_xor(o0b, 16); o0b += __shfl_xor(o0b, 32);
        o1b += __shfl_xor(o1b, 16); o1b += __shfl_xor(o1b, 32);
        trb += __shfl_xor(trb, 16); trb += __shfl_xor(trb, 32);

        int rowA = tA * 16 + col;
        if (lane < 16 && rowA < B) {
            out[3 * rowA + 0] = o0a + b30;
            out[3 * rowA + 1] = o1a + b31;
            out[3 * rowA + 2] = -tra;
        }
        int rowB = tB * 16 + col;
        if (lane < 16 && vB && rowB < B) {
            out[3 * rowB + 0] = o0b + b30;
            out[3 * rowB + 1] = o1b + b31;
            out[3 * rowB + 2] = -trb;
        }

        zvA = zvAn;
        zvB = zvBn;
    }
}

extern "C" void kernel_launch(void* const* d_in, const int* in_sizes, int n_in,
                              void* d_out, int out_size, void* d_ws, size_t ws_size,
                              hipStream_t stream) {
    // d_in: 0=t(unused) 1=z_and_logp 2=W1 3=b1 4=W2 5=b2 6=W3 7=b3
    const float* zin = (const float*)d_in[1];
    const float* W1  = (const float*)d_in[2];
    const float* b1  = (const float*)d_in[3];
    const float* W2  = (const float*)d_in[4];
    const float* b2  = (const float*)d_in[5];
    const float* W3  = (const float*)d_in[6];
    const float* b3  = (const float*)d_in[7];
    float* out = (float*)d_out;

    int B = in_sizes[1] / 3;
    int ntiles = (B + 15) / 16;
    int grid = 1536;   // 3 waves/SIMD -> 768 resident blocks -> 2 rounds
    odefunc_mfma<<<grid, 256, 0, stream>>>(zin, W1, b1, W2, b2, W3, b3,
                                           out, B, ntiles);
}

// Round 14
// 116.329 us; speedup vs baseline: 1.4754x; 1.4754x over previous
//
#include <hip/hip_runtime.h>
#include <hip/hip_fp16.h>

// ODEFunc CNF dynamics, B=1e6 rows, H=64:
//   h1 = elu(W1 z + b1); h2 = W2 h1 + b2; out01 = W3 elu(h2)+b3;
//   trace = sum_k elu'(h2_k) * (G ex1)_k with G[k,j]=W2[k,j]*(c_k w0_j + d_k w1_j)
//
// Ladder: R6 74 -> R8 62.5 -> R10 58 -> R11 2-tile 55.3 -> R12 f16 52 ->
// R16 consts->regs 49.5 -> R18 l2e-fold + f16 epilogue 46.5 (BEST) ->
// R19 (3,3) SPILL 104 (cap 168 < true footprint 176 = 112 arch + 64 AGPR;
// VGPR_Count EXCLUDES AGPRs — third time this bit; ledger final: only (2,2)
// cap 256 fits this structure).
// R20 (this): revert to R18 (2,2) + THIRD tile of ILP (48 rows/wave-iter).
//   At (2,2) VALUBusy ~50%: both waves stall together on dependent
//   exp/cvt chains; more waves impossible -> more independent chains per
//   wave. Measured-footprint check: 176 (2-tile) + 32 acc + 16 frag + ~5
//   = ~229 <= 256. Also amortizes z-shfl/loop overhead 3 ways.
//   Spill litmus: WRITE_SIZE must stay 11718.75 KB, FETCH ~5988 KB; if
//   ballooned, next round reverts to exact R18.
// Layouts (m120-verified): A[m=col][k=jt*32+quad*8+jj], B[k][n=col],
//   D[m=mt*16+quad*4+i][n=col].

typedef _Float16 f16x8 __attribute__((ext_vector_type(8)));
typedef _Float16 f16x2 __attribute__((ext_vector_type(2)));
typedef float    f32x4 __attribute__((ext_vector_type(4)));

static __device__ __forceinline__ f16x8 exp2_h8(f16x8 t) {
    f16x8 e;
#pragma unroll
    for (int p = 0; p < 4; ++p) {
        f16x2 t2 = {t[2*p], t[2*p+1]};
        __half2 r = h2exp2(__builtin_bit_cast(__half2, t2));
        f16x2 e2 = __builtin_bit_cast(f16x2, r);
        e[2*p] = e2[0]; e[2*p+1] = e2[1];
    }
    return e;
}

static __device__ __forceinline__ f16x2 exp2_h2(f16x2 t) {
    __half2 r = h2exp2(__builtin_bit_cast(__half2, t));
    return __builtin_bit_cast(f16x2, r);
}

static __device__ __forceinline__ f16x2 cvtpk(float a, float b) {
    return __builtin_bit_cast(f16x2, __builtin_amdgcn_cvt_pkrtz(a, b));
}

static __device__ __forceinline__ f16x8 bcast8(float z) {
    _Float16 h = (_Float16)z;
    f16x8 v = {h, h, h, h, h, h, h, h};
    return v;
}

__global__ __launch_bounds__(256) __attribute__((amdgpu_waves_per_eu(2, 2)))
void odefunc_mfma(const float* __restrict__ zin,
                  const float* __restrict__ W1, const float* __restrict__ b1,
                  const float* __restrict__ W2, const float* __restrict__ b2,
                  const float* __restrict__ W3, const float* __restrict__ b3,
                  float* __restrict__ out, int B, int ntiles)
{
    const float L2E  = 1.442695040888963f;
    const float RL2E = 0.6931471805599453f;   // 1/log2(e) = ln 2

    // LDS: one-shot staging for coalesced const loads (pre-scaled by l2e fold)
    __shared__ _Float16 sH[192];   // l2e*W1 col0 | l2e*W1 col1 | l2e*b1
    __shared__ f32x4    sC[48];    // l2e*b2 | W3row0/l2e | W3row1/l2e

    const int lane = threadIdx.x & 63;
    const int quad = lane >> 4;      // 0..3
    const int col  = lane & 15;      // row-within-tile

    if (threadIdx.x < 64) {
        int i = threadIdx.x;
        sH[i]       = (_Float16)(W1[2*i]     * L2E);
        sH[64 + i]  = (_Float16)(W1[2*i + 1] * L2E);
        sH[128 + i] = (_Float16)(b1[i]       * L2E);
        float* s = (float*)sC;
        s[i]       = b2[i] * L2E;
        s[64 + i]  = W3[i]      * RL2E;   // W3[0,:]/l2e
        s[128 + i] = W3[64 + i] * RL2E;   // W3[1,:]/l2e
    }

    const int wid    = blockIdx.x * (blockDim.x >> 6) + (threadIdx.x >> 6);
    const int nwaves = gridDim.x * (blockDim.x >> 6);

    // ---- Loop-invariant A-fragments (f16): W2 and G (trace-folded), UNSCALED ----
    f16x8 aW2[4][2], aG[4][2];
#pragma unroll
    for (int mt = 0; mt < 4; ++mt) {
        const int k = mt * 16 + col;
        const float ck = W3[k], dk = W3[64 + k];
#pragma unroll
        for (int jt = 0; jt < 2; ++jt) {
            const float* p = W2 + k * 64 + jt * 32 + quad * 8;
#pragma unroll
            for (int jj = 0; jj < 8; ++jj) {
                int j = jt * 32 + quad * 8 + jj;
                float w2 = p[jj];
                aW2[mt][jt][jj] = (_Float16)w2;
                aG[mt][jt][jj]  = (_Float16)(w2 * fmaf(ck, W1[2*j], dk * W1[2*j+1]));
            }
        }
    }

    const float b30 = b3[0], b31 = b3[1];
    const f32x4 zero4 = {0.f, 0.f, 0.f, 0.f};
    const _Float16 hl2e = (_Float16)L2E;
    const _Float16 h0   = (_Float16)0.0f;
    const f16x8 zero8 = {h0,h0,h0,h0,h0,h0,h0,h0};
    const f16x8 l2e8  = {hl2e,hl2e,hl2e,hl2e,hl2e,hl2e,hl2e,hl2e};
    const f16x8 ml2e8 = {-hl2e,-hl2e,-hl2e,-hl2e,-hl2e,-hl2e,-hl2e,-hl2e};
    const f16x2 zero2 = {h0, h0};
    const f16x2 l2e2  = {hl2e, hl2e};
    const f16x2 ml2e2 = {-hl2e, -hl2e};

    __syncthreads();

    // ---- hoist per-lane constants into registers ----
    f16x8 cw0[2], cw1[2], cbb[2];
#pragma unroll
    for (int jt = 0; jt < 2; ++jt) {
        int j0 = jt * 32 + quad * 8;
        cw0[jt] = *(const f16x8*)(sH + j0);
        cw1[jt] = *(const f16x8*)(sH + j0 + 64);
        cbb[jt] = *(const f16x8*)(sH + j0 + 128);
    }
    f32x4 cb2[4];
    f16x2 cw30h[4][2], cw31h[4][2];
#pragma unroll
    for (int mt = 0; mt < 4; ++mt) {
        int k4 = mt * 4 + quad;
        cb2[mt] = sC[k4];                       // l2e*b2 -> MFMA C-init
        f32x4 w30 = sC[k4 + 16];
        f32x4 w31 = sC[k4 + 32];
        cw30h[mt][0] = cvtpk(w30[0], w30[1]);
        cw30h[mt][1] = cvtpk(w30[2], w30[3]);
        cw31h[mt][0] = cvtpk(w31[0], w31[1]);
        cw31h[mt][1] = cvtpk(w31[2], w31[3]);
    }

    // ---- coalesced z: lanes 0-47 cover a tile's 16 rows x 3 floats ----
    const int lload = lane < 48 ? lane : 47;
    int tp = wid;                     // tile-triple index: tiles 3tp..3tp+2
    float zv[3] = {0.f, 0.f, 0.f};
#pragma unroll
    for (int t = 0; t < 3; ++t) {
        int tt = 3 * tp + t;
        if (tt < ntiles) zv[t] = zin[tt * 48 + lload];
    }

    for (; 3 * tp < ntiles; tp += nwaves) {
        // prefetch next triple's z (covered by this triple's compute)
        float zvn[3];
#pragma unroll
        for (int t = 0; t < 3; ++t) {
            int tt = 3 * (tp + nwaves) + t;
            zvn[t] = zin[(tt < ntiles ? tt : 0) * 48 + lload];
        }

        f16x8 z08[3], z18[3];
#pragma unroll
        for (int t = 0; t < 3; ++t) {
            z08[t] = bcast8(__shfl(zv[t], 3 * col));
            z18[t] = bcast8(__shfl(zv[t], 3 * col + 1));
        }

        // ---- layer 1: a' = l2e*a; e = exp2(min(a',0));
        //      Bh' = l2e*elu(a) = max(a', fma(l2e,e,-l2e)) — 3 indep chains ----
        f16x8 Bh[3][2], Be[3][2];
#pragma unroll
        for (int jt = 0; jt < 2; ++jt) {
#pragma unroll
            for (int t = 0; t < 3; ++t) {
                f16x8 a = __builtin_elementwise_fma(cw0[jt], z08[t],
                          __builtin_elementwise_fma(cw1[jt], z18[t], cbb[jt]));
                f16x8 e = exp2_h8(__builtin_elementwise_min(a, zero8));
                Bh[t][jt] = __builtin_elementwise_max(a,
                            __builtin_elementwise_fma(l2e8, e, ml2e8));
                Be[t][jt] = e;
            }
        }

        // ---- MFMA: accH = W2*(l2e*h) + l2e*b2; accT = G*e — 3 tiles ----
        f32x4 aH[3][4], aT[3][4];
#pragma unroll
        for (int mt = 0; mt < 4; ++mt) {
#pragma unroll
            for (int t = 0; t < 3; ++t) {
                aH[t][mt] = __builtin_amdgcn_mfma_f32_16x16x32_f16(aW2[mt][0], Bh[t][0], cb2[mt], 0, 0, 0);
                aH[t][mt] = __builtin_amdgcn_mfma_f32_16x16x32_f16(aW2[mt][1], Bh[t][1], aH[t][mt], 0, 0, 0);
                aT[t][mt] = __builtin_amdgcn_mfma_f32_16x16x32_f16(aG[mt][0], Be[t][0], zero4, 0, 0, 0);
                aT[t][mt] = __builtin_amdgcn_mfma_f32_16x16x32_f16(aG[mt][1], Be[t][1], aT[t][mt], 0, 0, 0);
            }
        }

        // ---- epilogue (packed f16): e2 = exp2(min(acc,0));
        //      hh' = max(acc, fma(l2e,e2,-l2e)); folds in pk_fma_f16 ----
        f16x2 o0[3] = {zero2, zero2, zero2};
        f16x2 o1[3] = {zero2, zero2, zero2};
        f16x2 tr[3] = {zero2, zero2, zero2};
#pragma unroll
        for (int mt = 0; mt < 4; ++mt) {
#pragma unroll
            for (int p = 0; p < 2; ++p) {
                f16x2 w30p = cw30h[mt][p], w31p = cw31h[mt][p];
#pragma unroll
                for (int t = 0; t < 3; ++t) {
                    f16x2 ah = cvtpk(aH[t][mt][2*p], aH[t][mt][2*p+1]);
                    f16x2 at = cvtpk(aT[t][mt][2*p], aT[t][mt][2*p+1]);
                    f16x2 e  = exp2_h2(__builtin_elementwise_min(ah, zero2));
                    f16x2 hh = __builtin_elementwise_max(ah,
                               __builtin_elementwise_fma(l2e2, e, ml2e2));
                    o0[t] = __builtin_elementwise_fma(w30p, hh, o0[t]);
                    o1[t] = __builtin_elementwise_fma(w31p, hh, o1[t]);
                    tr[t] = __builtin_elementwise_fma(e, at, tr[t]);
                }
            }
        }

        // ---- reduce (f32) + store, per tile ----
#pragma unroll
        for (int t = 0; t < 3; ++t) {
            float o0f = (float)o0[t][0] + (float)o0[t][1];
            float o1f = (float)o1[t][0] + (float)o1[t][1];
            float trf = (float)tr[t][0] + (float)tr[t][1];
            o0f += __shfl_xor(o0f, 16); o0f += __shfl_xor(o0f, 32);
            o1f += __shfl_xor(o1f, 16); o1f += __shfl_xor(o1f, 32);
            trf += __shfl_xor(trf, 16); trf += __shfl_xor(trf, 32);
            int tt = 3 * tp + t;
            int row = tt * 16 + col;
            if (lane < 16 && tt < ntiles && row < B) {
                out[3 * row + 0] = o0f + b30;
                out[3 * row + 1] = o1f + b31;
                out[3 * row + 2] = -trf;
            }
        }

#pragma unroll
        for (int t = 0; t < 3; ++t) zv[t] = zvn[t];
    }
}

extern "C" void kernel_launch(void* const* d_in, const int* in_sizes, int n_in,
                              void* d_out, int out_size, void* d_ws, size_t ws_size,
                              hipStream_t stream) {
    // d_in: 0=t(unused) 1=z_and_logp 2=W1 3=b1 4=W2 5=b2 6=W3 7=b3
    const float* zin = (const float*)d_in[1];
    const float* W1  = (const float*)d_in[2];
    const float* b1  = (const float*)d_in[3];
    const float* W2  = (const float*)d_in[4];
    const float* b2  = (const float*)d_in[5];
    const float* W3  = (const float*)d_in[6];
    const float* b3  = (const float*)d_in[7];
    float* out = (float*)d_out;

    int B = in_sizes[1] / 3;
    int ntiles = (B + 15) / 16;
    int grid = 1024;   // 2 waves/SIMD -> 512 resident blocks -> 2 rounds
    odefunc_mfma<<<grid, 256, 0, stream>>>(zin, W1, b1, W2, b2, W3, b3,
                                           out, B, ntiles);
}

// Round 15
// 113.035 us; speedup vs baseline: 1.5184x; 1.0291x over previous
//
#include <hip/hip_runtime.h>
#include <hip/hip_fp16.h>

// ODEFunc CNF dynamics, B=1e6 rows, H=64:
//   h1 = elu(W1 z + b1); h2 = W2 h1 + b2; out01 = W3 elu(h2)+b3;
//   trace = sum_k elu'(h2_k) * (G ex1)_k with G[k,j]=W2[k,j]*(c_k w0_j + d_k w1_j)
//
// Ladder: R6 74 -> R8 62.5 -> R10 58 -> R11 2-tile 55.3 -> R12 f16 52 ->
// R16 consts->regs 49.5 -> R18 l2e-fold + f16 epilogue 46.5 (BEST) ->
// R19 (3,3) SPILL 104 -> R20 3-tile ILP NULL 46.8.
// Occupancy/ILP record: more waves null (R15 +42% occ -> -3%), more in-wave
// ILP null (R20). VALUBusy pinned ~50% in all variants. R20 also exposed
// launch-geometry costs: 3-tile quantization (5.09 iters/wave -> 18% tail
// imbalance) and 2 residency rounds = 2x prologue (~700cyc W2/G build).
// R21 (this): exact R18 kernel (2-tile, (2,2)); single change: grid 512 =
//   2048 waves = one residency round (256CU x 4SIMD x 2waves).
//   - prologue once per wave slot (was 2x)
//   - 31250 pairs / 2048 waves = 15.26 iters: +-1 tail = 4.8% (3-tile: 18%)
//   - no inter-round block-swap gap
//   Spill litmus: WRITE_SIZE must stay 11718.75 KB, FETCH ~5988 KB.
// Layouts (m120-verified): A[m=col][k=jt*32+quad*8+jj], B[k][n=col],
//   D[m=mt*16+quad*4+i][n=col].

typedef _Float16 f16x8 __attribute__((ext_vector_type(8)));
typedef _Float16 f16x2 __attribute__((ext_vector_type(2)));
typedef float    f32x4 __attribute__((ext_vector_type(4)));

static __device__ __forceinline__ f16x8 exp2_h8(f16x8 t) {
    f16x8 e;
#pragma unroll
    for (int p = 0; p < 4; ++p) {
        f16x2 t2 = {t[2*p], t[2*p+1]};
        __half2 r = h2exp2(__builtin_bit_cast(__half2, t2));
        f16x2 e2 = __builtin_bit_cast(f16x2, r);
        e[2*p] = e2[0]; e[2*p+1] = e2[1];
    }
    return e;
}

static __device__ __forceinline__ f16x2 exp2_h2(f16x2 t) {
    __half2 r = h2exp2(__builtin_bit_cast(__half2, t));
    return __builtin_bit_cast(f16x2, r);
}

static __device__ __forceinline__ f16x2 cvtpk(float a, float b) {
    return __builtin_bit_cast(f16x2, __builtin_amdgcn_cvt_pkrtz(a, b));
}

__global__ __launch_bounds__(256) __attribute__((amdgpu_waves_per_eu(2, 2)))
void odefunc_mfma(const float* __restrict__ zin,
                  const float* __restrict__ W1, const float* __restrict__ b1,
                  const float* __restrict__ W2, const float* __restrict__ b2,
                  const float* __restrict__ W3, const float* __restrict__ b3,
                  float* __restrict__ out, int B, int ntiles)
{
    const float L2E  = 1.442695040888963f;
    const float RL2E = 0.6931471805599453f;   // 1/log2(e) = ln 2

    // LDS: one-shot staging for coalesced const loads (pre-scaled by l2e fold)
    __shared__ _Float16 sH[192];   // l2e*W1 col0 | l2e*W1 col1 | l2e*b1
    __shared__ f32x4    sC[48];    // l2e*b2 | W3row0/l2e | W3row1/l2e

    const int lane = threadIdx.x & 63;
    const int quad = lane >> 4;      // 0..3
    const int col  = lane & 15;      // row-within-tile

    if (threadIdx.x < 64) {
        int i = threadIdx.x;
        sH[i]       = (_Float16)(W1[2*i]     * L2E);
        sH[64 + i]  = (_Float16)(W1[2*i + 1] * L2E);
        sH[128 + i] = (_Float16)(b1[i]       * L2E);
        float* s = (float*)sC;
        s[i]       = b2[i] * L2E;
        s[64 + i]  = W3[i]      * RL2E;   // W3[0,:]/l2e
        s[128 + i] = W3[64 + i] * RL2E;   // W3[1,:]/l2e
    }

    const int wid    = blockIdx.x * (blockDim.x >> 6) + (threadIdx.x >> 6);
    const int nwaves = gridDim.x * (blockDim.x >> 6);

    // ---- Loop-invariant A-fragments (f16): W2 and G (trace-folded), UNSCALED ----
    f16x8 aW2[4][2], aG[4][2];
#pragma unroll
    for (int mt = 0; mt < 4; ++mt) {
        const int k = mt * 16 + col;
        const float ck = W3[k], dk = W3[64 + k];
#pragma unroll
        for (int jt = 0; jt < 2; ++jt) {
            const float* p = W2 + k * 64 + jt * 32 + quad * 8;
#pragma unroll
            for (int jj = 0; jj < 8; ++jj) {
                int j = jt * 32 + quad * 8 + jj;
                float w2 = p[jj];
                aW2[mt][jt][jj] = (_Float16)w2;
                aG[mt][jt][jj]  = (_Float16)(w2 * fmaf(ck, W1[2*j], dk * W1[2*j+1]));
            }
        }
    }

    const float b30 = b3[0], b31 = b3[1];
    const f32x4 zero4 = {0.f, 0.f, 0.f, 0.f};
    const _Float16 hl2e = (_Float16)L2E;
    const _Float16 h0   = (_Float16)0.0f;
    const f16x8 zero8 = {h0,h0,h0,h0,h0,h0,h0,h0};
    const f16x8 l2e8  = {hl2e,hl2e,hl2e,hl2e,hl2e,hl2e,hl2e,hl2e};
    const f16x8 ml2e8 = {-hl2e,-hl2e,-hl2e,-hl2e,-hl2e,-hl2e,-hl2e,-hl2e};
    const f16x2 zero2 = {h0, h0};
    const f16x2 l2e2  = {hl2e, hl2e};
    const f16x2 ml2e2 = {-hl2e, -hl2e};

    __syncthreads();

    // ---- hoist per-lane constants into registers ----
    f16x8 cw0[2], cw1[2], cbb[2];
#pragma unroll
    for (int jt = 0; jt < 2; ++jt) {
        int j0 = jt * 32 + quad * 8;
        cw0[jt] = *(const f16x8*)(sH + j0);
        cw1[jt] = *(const f16x8*)(sH + j0 + 64);
        cbb[jt] = *(const f16x8*)(sH + j0 + 128);
    }
    f32x4 cb2[4];
    f16x2 cw30h[4][2], cw31h[4][2];
#pragma unroll
    for (int mt = 0; mt < 4; ++mt) {
        int k4 = mt * 4 + quad;
        cb2[mt] = sC[k4];                       // l2e*b2 -> MFMA C-init
        f32x4 w30 = sC[k4 + 16];
        f32x4 w31 = sC[k4 + 32];
        cw30h[mt][0] = cvtpk(w30[0], w30[1]);
        cw30h[mt][1] = cvtpk(w30[2], w30[3]);
        cw31h[mt][0] = cvtpk(w31[0], w31[1]);
        cw31h[mt][1] = cvtpk(w31[2], w31[3]);
    }

    // ---- coalesced z: lanes 0-47 cover a tile's 16 rows x 3 floats ----
    const int lload = lane < 48 ? lane : 47;
    int tp = wid;                     // tile-pair index: tiles 2tp, 2tp+1
    float zvA = 0.f, zvB = 0.f;
    if (2 * tp < ntiles) {
        zvA = zin[(2 * tp) * 48 + lload];
        if (2 * tp + 1 < ntiles) zvB = zin[(2 * tp + 1) * 48 + lload];
    }

    for (; 2 * tp < ntiles; tp += nwaves) {
        const int tA = 2 * tp, tB = 2 * tp + 1;
        const bool vB = tB < ntiles;

        // prefetch next pair's z (covered by this pair's ~4k-cycle body)
        int tpn = tp + nwaves;
        int tAn = 2 * tpn     < ntiles ? 2 * tpn     : 0;
        int tBn = 2 * tpn + 1 < ntiles ? 2 * tpn + 1 : 0;
        float zvAn = zin[tAn * 48 + lload];
        float zvBn = zin[tBn * 48 + lload];

        float z0A = __shfl(zvA, 3 * col), z1A = __shfl(zvA, 3 * col + 1);
        float z0B = __shfl(zvB, 3 * col), z1B = __shfl(zvB, 3 * col + 1);
        const _Float16 z0Ah = (_Float16)z0A, z1Ah = (_Float16)z1A;
        const _Float16 z0Bh = (_Float16)z0B, z1Bh = (_Float16)z1B;
        const f16x8 z0A8 = {z0Ah,z0Ah,z0Ah,z0Ah,z0Ah,z0Ah,z0Ah,z0Ah};
        const f16x8 z1A8 = {z1Ah,z1Ah,z1Ah,z1Ah,z1Ah,z1Ah,z1Ah,z1Ah};
        const f16x8 z0B8 = {z0Bh,z0Bh,z0Bh,z0Bh,z0Bh,z0Bh,z0Bh,z0Bh};
        const f16x8 z1B8 = {z1Bh,z1Bh,z1Bh,z1Bh,z1Bh,z1Bh,z1Bh,z1Bh};

        // ---- layer 1: a' = l2e*a (pre-scaled consts); e = exp2(min(a',0));
        //      Bh' = l2e*elu(a) = max(a', fma(l2e,e,-l2e)) ----
        f16x8 BhA[2], BeA[2], BhB[2], BeB[2];
#pragma unroll
        for (int jt = 0; jt < 2; ++jt) {
            // tile A
            f16x8 aA = __builtin_elementwise_fma(cw0[jt], z0A8,
                       __builtin_elementwise_fma(cw1[jt], z1A8, cbb[jt]));
            f16x8 eA = exp2_h8(__builtin_elementwise_min(aA, zero8));
            f16x8 hA = __builtin_elementwise_max(aA,
                       __builtin_elementwise_fma(l2e8, eA, ml2e8));
            // tile B (independent chain)
            f16x8 aB = __builtin_elementwise_fma(cw0[jt], z0B8,
                       __builtin_elementwise_fma(cw1[jt], z1B8, cbb[jt]));
            f16x8 eB = exp2_h8(__builtin_elementwise_min(aB, zero8));
            f16x8 hB = __builtin_elementwise_max(aB,
                       __builtin_elementwise_fma(l2e8, eB, ml2e8));
            BhA[jt] = hA; BeA[jt] = eA;
            BhB[jt] = hB; BeB[jt] = eB;
        }

        // ---- MFMA: accH = W2*(l2e*h) + l2e*b2 = l2e*h2pre; accT = G*e ----
        f32x4 aHA[4], aTA[4], aHB[4], aTB[4];
#pragma unroll
        for (int mt = 0; mt < 4; ++mt) {
            aHA[mt] = __builtin_amdgcn_mfma_f32_16x16x32_f16(aW2[mt][0], BhA[0], cb2[mt], 0, 0, 0);
            aHA[mt] = __builtin_amdgcn_mfma_f32_16x16x32_f16(aW2[mt][1], BhA[1], aHA[mt], 0, 0, 0);
            aHB[mt] = __builtin_amdgcn_mfma_f32_16x16x32_f16(aW2[mt][0], BhB[0], cb2[mt], 0, 0, 0);
            aHB[mt] = __builtin_amdgcn_mfma_f32_16x16x32_f16(aW2[mt][1], BhB[1], aHB[mt], 0, 0, 0);
            aTA[mt] = __builtin_amdgcn_mfma_f32_16x16x32_f16(aG[mt][0], BeA[0], zero4, 0, 0, 0);
            aTA[mt] = __builtin_amdgcn_mfma_f32_16x16x32_f16(aG[mt][1], BeA[1], aTA[mt], 0, 0, 0);
            aTB[mt] = __builtin_amdgcn_mfma_f32_16x16x32_f16(aG[mt][0], BeB[0], zero4, 0, 0, 0);
            aTB[mt] = __builtin_amdgcn_mfma_f32_16x16x32_f16(aG[mt][1], BeB[1], aTB[mt], 0, 0, 0);
        }

        // ---- epilogue (packed f16, true double-rate): e2 = exp2(min(acc,0));
        //      hh' = max(acc, fma(l2e,e2,-l2e)); folds in pk_fma_f16 ----
        f16x2 o0A2 = zero2, o1A2 = zero2, trA2 = zero2;
        f16x2 o0B2 = zero2, o1B2 = zero2, trB2 = zero2;
#pragma unroll
        for (int mt = 0; mt < 4; ++mt) {
#pragma unroll
            for (int p = 0; p < 2; ++p) {
                f16x2 w30p = cw30h[mt][p], w31p = cw31h[mt][p];
                // tile A
                f16x2 ahA = cvtpk(aHA[mt][2*p], aHA[mt][2*p+1]);
                f16x2 atA = cvtpk(aTA[mt][2*p], aTA[mt][2*p+1]);
                f16x2 eA  = exp2_h2(__builtin_elementwise_min(ahA, zero2));
                f16x2 hhA = __builtin_elementwise_max(ahA,
                            __builtin_elementwise_fma(l2e2, eA, ml2e2));
                o0A2 = __builtin_elementwise_fma(w30p, hhA, o0A2);
                o1A2 = __builtin_elementwise_fma(w31p, hhA, o1A2);
                trA2 = __builtin_elementwise_fma(eA, atA, trA2);
                // tile B
                f16x2 ahB = cvtpk(aHB[mt][2*p], aHB[mt][2*p+1]);
                f16x2 atB = cvtpk(aTB[mt][2*p], aTB[mt][2*p+1]);
                f16x2 eB  = exp2_h2(__builtin_elementwise_min(ahB, zero2));
                f16x2 hhB = __builtin_elementwise_max(ahB,
                            __builtin_elementwise_fma(l2e2, eB, ml2e2));
                o0B2 = __builtin_elementwise_fma(w30p, hhB, o0B2);
                o1B2 = __builtin_elementwise_fma(w31p, hhB, o1B2);
                trB2 = __builtin_elementwise_fma(eB, atB, trB2);
            }
        }
        float o0a = (float)o0A2[0] + (float)o0A2[1];
        float o1a = (float)o1A2[0] + (float)o1A2[1];
        float tra = (float)trA2[0] + (float)trA2[1];
        float o0b = (float)o0B2[0] + (float)o0B2[1];
        float o1b = (float)o1B2[0] + (float)o1B2[1];
        float trb = (float)trB2[0] + (float)trB2[1];

        // ---- cross-quad reduction (k spans quads): 2 butterfly stages, f32 ----
        o0a += __shfl_xor(o0a, 16); o0a += __shfl_xor(o0a, 32);
        o1a += __shfl_xor(o1a, 16); o1a += __shfl_xor(o1a, 32);
        tra += __shfl_xor(tra, 16); tra += __shfl_xor(tra, 32);
        o0b += __shfl_xor(o0b, 16); o0b += __shfl_xor(o0b, 32);
        o1b += __shfl_xor(o1b, 16); o1b += __shfl_xor(o1b, 32);
        trb += __shfl_xor(trb, 16); trb += __shfl_xor(trb, 32);

        int rowA = tA * 16 + col;
        if (lane < 16 && rowA < B) {
            out[3 * rowA + 0] = o0a + b30;
            out[3 * rowA + 1] = o1a + b31;
            out[3 * rowA + 2] = -tra;
        }
        int rowB = tB * 16 + col;
        if (lane < 16 && vB && rowB < B) {
            out[3 * rowB + 0] = o0b + b30;
            out[3 * rowB + 1] = o1b + b31;
            out[3 * rowB + 2] = -trb;
        }

        zvA = zvAn;
        zvB = zvBn;
    }
}

extern "C" void kernel_launch(void* const* d_in, const int* in_sizes, int n_in,
                              void* d_out, int out_size, void* d_ws, size_t ws_size,
                              hipStream_t stream) {
    // d_in: 0=t(unused) 1=z_and_logp 2=W1 3=b1 4=W2 5=b2 6=W3 7=b3
    const float* zin = (const float*)d_in[1];
    const float* W1  = (const float*)d_in[2];
    const float* b1  = (const float*)d_in[3];
    const float* W2  = (const float*)d_in[4];
    const float* b2  = (const float*)d_in[5];
    const float* W3  = (const float*)d_in[6];
    const float* b3  = (const float*)d_in[7];
    float* out = (float*)d_out;

    int B = in_sizes[1] / 3;
    int ntiles = (B + 15) / 16;
    int grid = 512;   // 2048 waves = 256CU x 4SIMD x 2 waves: ONE residency
                      // round; prologue once per slot; 15.26 iters/wave
    odefunc_mfma<<<grid, 256, 0, stream>>>(zin, W1, b1, W2, b2, W3, b3,
                                           out, B, ntiles);
}